// Round 16
// baseline (210.055 us; speedup 1.0000x reference)
//
#include <hip/hip_runtime.h>
#include <hip/hip_fp16.h>

#define N_SIG (1 << 23)   // 8388608
#define N2    (1 << 24)   // padded FFT length = 256^3
#define MH    (1 << 23)   // half length M = 2^23

// ---------------------------------------------------------------------------
// packed-f32 complex type
// ---------------------------------------------------------------------------
typedef float v2f __attribute__((ext_vector_type(2)));

__device__ __forceinline__ v2f mk(float x, float y) { v2f r; r.x = x; r.y = y; return r; }
__device__ __forceinline__ v2f cmul(v2f a, v2f b) {
    return mk(a.x, a.x) * b + mk(-a.y, a.y) * __builtin_shufflevector(b, b, 1, 0);
}
__device__ __forceinline__ v2f mulnegi(v2f a) { return mk(a.y, -a.x); }   // -i*a
__device__ __forceinline__ v2f conjv(v2f a)  { return mk(a.x, -a.y); }

__device__ __forceinline__ v2f h2f(__half2 h) {
    return mk(__low2float(h), __high2float(h));
}
__device__ __forceinline__ __half2 f2h(v2f f) {
    return __float22half2_rn(make_float2(f.x, f.y));
}

// exp(-2*pi*i*f), f in revolutions
__device__ __forceinline__ v2f twid(float f) {
    float s, c;
#if __has_builtin(__builtin_amdgcn_sinf) && __has_builtin(__builtin_amdgcn_cosf)
    s = __builtin_amdgcn_sinf(f);
    c = __builtin_amdgcn_cosf(f);
#else
    __sincosf(6.28318530717958647693f * f, &s, &c);
#endif
    return mk(c, -s);
}

// radix-4 DIF butterfly
__device__ __forceinline__ void bfly4(v2f c0, v2f c1, v2f c2, v2f c3,
                                      v2f& e0, v2f& e1, v2f& e2, v2f& e3) {
    v2f d0 = c0 + c2, d1 = c0 - c2;
    v2f d2 = c1 + c3, d3 = mulnegi(c1 - c3);
    e0 = d0 + d2; e1 = d1 + d3; e2 = d0 - d2; e3 = d1 - d3;
}

// 16-point DFT, natural order in/out
__device__ __forceinline__ void fft16(v2f v[16]) {
    const float C1 = 0.92387953251128675613f;
    const float S1 = 0.38268343236508977173f;
    const float RH = 0.70710678118654752440f;
    const v2f W1 = mk( C1, -S1);
    const v2f W2 = mk( RH, -RH);
    const v2f W3 = mk( S1, -C1);
    const v2f W6 = mk(-RH, -RH);
    const v2f W9 = mk(-C1,  S1);
    v2f t[16];
    { v2f e0,e1,e2,e3; bfly4(v[0],v[4],v[8],v[12], e0,e1,e2,e3);
      t[0]=e0; t[1]=e1; t[2]=e2; t[3]=e3; }
    { v2f e0,e1,e2,e3; bfly4(v[1],v[5],v[9],v[13], e0,e1,e2,e3);
      t[4]=e0; t[5]=cmul(e1,W1); t[6]=cmul(e2,W2); t[7]=cmul(e3,W3); }
    { v2f e0,e1,e2,e3; bfly4(v[2],v[6],v[10],v[14], e0,e1,e2,e3);
      t[8]=e0; t[9]=cmul(e1,W2); t[10]=mulnegi(e2); t[11]=cmul(e3,W6); }
    { v2f e0,e1,e2,e3; bfly4(v[3],v[7],v[11],v[15], e0,e1,e2,e3);
      t[12]=e0; t[13]=cmul(e1,W3); t[14]=cmul(e2,W6); t[15]=cmul(e3,W9); }
    { v2f e0,e1,e2,e3; bfly4(t[0],t[4],t[8],t[12], e0,e1,e2,e3);
      v[0]=e0; v[4]=e1; v[8]=e2; v[12]=e3; }
    { v2f e0,e1,e2,e3; bfly4(t[1],t[5],t[9],t[13], e0,e1,e2,e3);
      v[1]=e0; v[5]=e1; v[9]=e2; v[13]=e3; }
    { v2f e0,e1,e2,e3; bfly4(t[2],t[6],t[10],t[14], e0,e1,e2,e3);
      v[2]=e0; v[6]=e1; v[10]=e2; v[14]=e3; }
    { v2f e0,e1,e2,e3; bfly4(t[3],t[7],t[11],t[15], e0,e1,e2,e3);
      v[3]=e0; v[7]=e1; v[11]=e2; v[15]=e3; }
}

// 8-point DFT, natural order in/out
__device__ __forceinline__ void fft8(v2f v[8]) {
    const float RH = 0.70710678118654752440f;
    v2f e0,e1,e2,e3, o0,o1,o2,o3;
    bfly4(v[0],v[2],v[4],v[6], e0,e1,e2,e3);
    bfly4(v[1],v[3],v[5],v[7], o0,o1,o2,o3);
    o1 = cmul(o1, mk( RH,-RH));
    o2 = mulnegi(o2);
    o3 = cmul(o3, mk(-RH,-RH));
    v[0]=e0+o0; v[4]=e0-o0;
    v[1]=e1+o1; v[5]=e1-o1;
    v[2]=e2+o2; v[6]=e2-o2;
    v[3]=e3+o3; v[7]=e3-o3;
}

// Scaled W for stored Z_s = Z * 2^-2: returns W * 2^-14
__device__ __forceinline__ v2f Wfun_s(v2f sk, v2f sr) {
    v2f a2 = cmul(sk, sk);
    v2f cs = conjv(sr);
    v2f b2 = cmul(cs, cs);
    v2f d  = a2 - b2;
    return mulnegi(d) * (1.0f / 4096.0f);
}

// ---------------------------------------------------------------------------
// 1024-thread geometry: tile = 64 cols x 256 q (radix-256) / 128 x 128 (r-128).
// thread = (col = t&63, sl = t>>6); a WAVE's 64 lanes span 64 consecutive cols
// -> every global load/store instruction covers a 256B contiguous segment.
// LDS: 64 KB exact, XOR swizzle p ^ (col&31) (round-13-proven; 2-way banks).
// MODE 0: fwd A (N2, l=65536), pack fused, staged j-major out
// MODE 1: fwd B (N2, l=256),   direct k-major store
// MODE 2: fwd C (N2, l=1),     direct store, Z_s = Z*2^-2
// MODE 3: inv A (M, l=32768),  pw fused + mirror-pair XCD swizzle (512 blocks)
// MODE 4: inv B (M, l=128),    direct store, amp 2^-4
// MODE 5: inv C (M, radix-128),fp32 interleaved-real out, *0.5
// Arithmetic identical to rounds 13/15 -> absmax must stay 64.
// ---------------------------------------------------------------------------
template<int MODE>
__global__ __launch_bounds__(1024, 8)
void fft_pass(const float* __restrict__ ga, const float* __restrict__ gx,
              const __half2* __restrict__ gin, __half2* __restrict__ gout,
              float2* __restrict__ goutF) {
    __shared__ __half2 tile[16384];   // exactly 64 KB
    const int t = threadIdx.x;
    int blk = blockIdx.x;
    if constexpr (MODE == 3) {
        // mirror-pair XCD swizzle over 512 blocks: regions p and 511-p placed
        // 8 apart in blockIdx -> same XCD under round-robin assignment
        int g = blk >> 4, i = blk & 15;
        blk = (i < 8) ? (8 * g + i) : (511 - (8 * g + (i - 8)));
    }

    if constexpr (MODE == 5) {
        // ---- radix-128 final pass: 128 cols x 128 q ----
        const int col = t & 127;
        const int sl  = t >> 7;           // u1-base (layer1) / r2 (layer2), [0,8)
        const int mk_ = col & 31;
        const int cb  = col << 7;         // col * 128
        const int bi  = blk * 128 + col;

        v2f va[8], vb[8];
        #pragma unroll
        for (int u2 = 0; u2 < 8; ++u2)
            va[u2] = h2f(gin[bi + ((sl + 16 * u2) << 16)]);
        #pragma unroll
        for (int u2 = 0; u2 < 8; ++u2)
            vb[u2] = h2f(gin[bi + ((sl + 8 + 16 * u2) << 16)]);
        fft8(va); fft8(vb);
        {   // layer-1 twiddles via recurrence (chain <= 7)
            v2f w1a = twid((float)sl * (1.0f / 128.0f));
            v2f w1b = twid((float)(sl + 8) * (1.0f / 128.0f));
            v2f ca = w1a, cb2 = w1b;
            va[1] = cmul(va[1], ca); vb[1] = cmul(vb[1], cb2);
            #pragma unroll
            for (int r2 = 2; r2 < 8; ++r2) {
                ca = cmul(ca, w1a);  va[r2] = cmul(va[r2], ca);
                cb2 = cmul(cb2, w1b); vb[r2] = cmul(vb[r2], cb2);
            }
        }
        #pragma unroll
        for (int r2 = 0; r2 < 8; ++r2) {
            tile[cb + ((sl + 16 * r2) ^ mk_)]     = f2h(va[r2]);
            tile[cb + ((sl + 8 + 16 * r2) ^ mk_)] = f2h(vb[r2]);
        }
        __syncthreads();
        v2f w[16];
        #pragma unroll
        for (int q1 = 0; q1 < 16; ++q1)
            w[q1] = h2f(tile[cb + ((q1 + 16 * sl) ^ mk_)]);
        fft16(w);   // w[r1] -> output r = sl + 8*r1, keep r < 64

        const float sc = 0.5f;            // accumulated scale; y = G/2^23
        #pragma unroll
        for (int r1 = 0; r1 < 8; ++r1) {
            int r = sl + 8 * r1;
            goutF[bi + (r << 16)] = make_float2(w[r1].x * sc, -w[r1].y * sc);
        }
        return;
    } else {
        // ---- radix-256 pass: 64 cols x 256 q ----
        const int col = t & 63;
        const int sl  = t >> 6;           // u1 (layer1) / r2 (layer2), [0,16)
        const int mk_ = col & 31;
        const int cb  = col << 8;         // col * 256
        v2f v[16];
        int jt = 0;

        if constexpr (MODE == 0) {        // fwd A, pack fused (q>=128 zero)
            int j = blk * 64 + col;
            jt = j;
            #pragma unroll
            for (int u2 = 0; u2 < 16; ++u2) {
                if (u2 < 8) {
                    int g = j + ((sl + 16 * u2) << 16);   // < N_SIG
                    v[u2] = mk(ga[g], gx[g]);
                } else {
                    v[u2] = mk(0.f, 0.f);
                }
            }
        } else if constexpr (MODE == 3) { // inv A: pw fused, contiguous-j gather
            int j = blk * 64 + col;       // j in [0, 2^15)
            jt = j;
            const float RH = 0.70710678118654752440f;
            v2f eb = twid((float)(j + (sl << 15)) * (1.0f / 16777216.0f));
            const v2f estep = mk(0.98078528040323044913f, -0.19509032201612826785f);
            v2f ec = eb;
            #pragma unroll
            for (int u2 = 0; u2 < 16; ++u2) {
                int tp = j + ((sl + 16 * u2) << 15);        // [0, M)
                v2f z1 = h2f(gin[tp]);                      // Z[t]
                v2f z2 = h2f(gin[tp + MH]);                 // Z[t+M]
                v2f z3 = h2f(gin[(N2 - tp) & (N2 - 1)]);    // Z[N2-t]
                v2f z4 = h2f(gin[MH - tp]);                 // Z[M-t]
                v2f Wt  = Wfun_s(z1, z3);
                v2f WtM = Wfun_s(z2, z4);
                v2f S = (Wt + WtM) * 0.5f;
                v2f D = (Wt - WtM) * 0.5f;
                v2f T = cmul(conjv(ec), D);                 // e^{+i th} * D
                v2f U = S + mk(-T.y, T.x);                  // S + i*T
                v[u2] = conjv(U);                           // P_s[t]
                if (u2 == 3)       ec = cmul(eb, mk(RH, -RH));   // *twid(1/8)
                else if (u2 == 7)  ec = mulnegi(eb);             // *twid(1/4)
                else if (u2 == 11) ec = cmul(eb, mk(-RH, -RH));  // *twid(3/8)
                else               ec = cmul(ec, estep);
            }
        } else if constexpr (MODE == 1) { // fwd B
            int jB = blk >> 2, k0 = (blk & 3) * 64;
            int bi = k0 + col + (jB << 8);
            jt = jB;
            #pragma unroll
            for (int u2 = 0; u2 < 16; ++u2)
                v[u2] = h2f(gin[bi + ((sl + 16 * u2) << 16)]);
        } else if constexpr (MODE == 4) { // inv B (half length, stride 2^15)
            int jB = blk >> 2, k0 = (blk & 3) * 64;
            int bi = k0 + col + (jB << 8);
            jt = jB;
            #pragma unroll
            for (int u2 = 0; u2 < 16; ++u2)
                v[u2] = h2f(gin[bi + ((sl + 16 * u2) << 15)]);
        } else {                          // MODE 2: fwd C
            int bi = blk * 64 + col;
            #pragma unroll
            for (int u2 = 0; u2 < 16; ++u2)
                v[u2] = h2f(gin[bi + ((sl + 16 * u2) << 16)]);
        }

        // layer 1: FFT16 over u2, twiddle W256^{sl*r2}, reseed at r=8
        fft16(v);
        {
            v2f w1 = twid((float)sl * (1.0f / 256.0f));
            v2f w8 = twid((float)sl * (1.0f / 32.0f));
            v2f cw = w1;
            v[1] = cmul(v[1], cw);
            #pragma unroll
            for (int r = 2; r < 16; ++r) {
                cw = (r == 8) ? w8 : cmul(cw, w1);
                v[r] = cmul(v[r], cw);
            }
        }

        // transpose: write p = sl + 16*r2, XOR swizzle
        #pragma unroll
        for (int r = 0; r < 16; ++r)
            tile[cb + ((sl + 16 * r) ^ mk_)] = f2h(v[r]);
        __syncthreads();
        v2f w[16];
        #pragma unroll
        for (int u1 = 0; u1 < 16; ++u1)
            w[u1] = h2f(tile[cb + ((u1 + 16 * sl) ^ mk_)]);
        if constexpr (MODE == 0 || MODE == 3)
            __syncthreads();               // readers done before staging overwrite

        fft16(w);

        // outer twiddle base*step^r1 (reseed at r1=8); MODE3/4 fold 2^-4
        if constexpr (MODE != 2) {
            float base_rev, step_rev, amp;
            if constexpr (MODE == 0) {        // D = 2^24
                base_rev = (float)(jt * sl) * (1.0f / 16777216.0f);
                step_rev = (float)jt * (1.0f / 1048576.0f);
                amp = 1.0f;
            } else if constexpr (MODE == 3) { // D = 2^23
                base_rev = (float)(jt * sl) * (1.0f / 8388608.0f);
                step_rev = (float)jt * (1.0f / 524288.0f);
                amp = 0.0625f;
            } else if constexpr (MODE == 1) { // D = 65536
                base_rev = (float)(jt * sl) * (1.0f / 65536.0f);
                step_rev = (float)jt * (1.0f / 4096.0f);
                amp = 1.0f;
            } else {                          // MODE 4: D = 32768
                base_rev = (float)(jt * sl) * (1.0f / 32768.0f);
                step_rev = (float)jt * (1.0f / 2048.0f);
                amp = 0.0625f;
            }
            v2f b0 = twid(base_rev) * amp;
            v2f os = twid(step_rev);
            v2f b8 = twid(base_rev + 8.0f * step_rev) * amp;
            v2f ob = b0;
            w[0] = cmul(w[0], ob);
            #pragma unroll
            for (int r1 = 1; r1 < 16; ++r1) {
                ob = (r1 == 8) ? b8 : cmul(ob, os);
                w[r1] = cmul(w[r1], ob);
            }
        }

        if constexpr (MODE == 0 || MODE == 3) {
            // j-major out[256 j + r], j = blk*64 + col: stage at p = sl+16*r1,
            // then one 16384-element linear sweep (16/thread, 64B contiguous)
            #pragma unroll
            for (int r1 = 0; r1 < 16; ++r1)
                tile[cb + ((sl + 16 * r1) ^ mk_)] = f2h(w[r1]);
            __syncthreads();
            int base = blk << 14;
            int rr = t >> 4;                 // output col [0,64)
            int c0 = (t & 15) << 4;          // r base
            int rbq = rr << 8;
            int rm = rr & 31;
            __half2* gp = &gout[base + (t << 4)];
            #pragma unroll
            for (int i = 0; i < 16; ++i)
                gp[i] = tile[rbq + ((c0 + i) ^ rm)];
        } else if constexpr (MODE == 1 || MODE == 4) {
            // k-major out[k + 65536 j + 256 r]: direct, 64-lane 256B runs
            int jB = blk >> 2, k0 = (blk & 3) * 64;
            int base = k0 + (jB << 16) + col;
            #pragma unroll
            for (int r1 = 0; r1 < 16; ++r1)
                gout[base + ((sl + 16 * r1) << 8)] = f2h(w[r1]);
        } else {
            // MODE 2: out[k + 65536 r]: direct, Z_s = Z * 2^-2
            int base = blk * 64 + col;
            #pragma unroll
            for (int r1 = 0; r1 < 16; ++r1)
                gout[base + ((sl + 16 * r1) << 16)] = f2h(w[r1] * 0.25f);
        }
    }
}

extern "C" void kernel_launch(void* const* d_in, const int* in_sizes, int n_in,
                              void* d_out, int out_size, void* d_ws, size_t ws_size,
                              hipStream_t stream) {
    const float* a = (const float*)d_in[0];
    const float* x = (const float*)d_in[1];
    float2* out2 = (float2*)d_out;

    __half2* buf0 = (__half2*)d_ws;     // 64 MB
    __half2* buf1 = buf0 + N2;          // 64 MB

    dim3 b(1024);
    // forward FFT of z = a + i*x, length 2^24
    fft_pass<0><<<1024, b, 0, stream>>>(a, x, nullptr, buf0, nullptr);
    fft_pass<1><<<1024, b, 0, stream>>>(nullptr, nullptr, buf0, buf1, nullptr);
    fft_pass<2><<<1024, b, 0, stream>>>(nullptr, nullptr, buf1, buf0, nullptr);
    // inverse via half-length forward FFT; Hermitian pointwise fused into the
    // stage-A load; mirror-pair XCD swizzle makes mirror gathers L2-local
    fft_pass<3><<<512, b, 0, stream>>>(nullptr, nullptr, buf0, buf1, nullptr);
    fft_pass<4><<<512, b, 0, stream>>>(nullptr, nullptr, buf1, buf0, nullptr);
    fft_pass<5><<<512, b, 0, stream>>>(nullptr, nullptr, buf0, nullptr, out2);
}

// Round 17
// 172.255 us; speedup vs baseline: 1.2194x; 1.2194x over previous
//
#include <hip/hip_runtime.h>
#include <hip/hip_fp16.h>

#define N_SIG (1 << 23)   // 8388608
#define N2    (1 << 24)   // padded FFT length = 256^3
#define MH    (1 << 23)   // half length M = 2^23

// ---------------------------------------------------------------------------
// packed-f32 complex type
// ---------------------------------------------------------------------------
typedef float v2f __attribute__((ext_vector_type(2)));

__device__ __forceinline__ v2f mk(float x, float y) { v2f r; r.x = x; r.y = y; return r; }
__device__ __forceinline__ v2f cmul(v2f a, v2f b) {
    return mk(a.x, a.x) * b + mk(-a.y, a.y) * __builtin_shufflevector(b, b, 1, 0);
}
__device__ __forceinline__ v2f mulnegi(v2f a) { return mk(a.y, -a.x); }   // -i*a
__device__ __forceinline__ v2f conjv(v2f a)  { return mk(a.x, -a.y); }

__device__ __forceinline__ v2f h2f(__half2 h) {
    return mk(__low2float(h), __high2float(h));
}
__device__ __forceinline__ __half2 f2h(v2f f) {
    return __float22half2_rn(make_float2(f.x, f.y));
}

// exp(-2*pi*i*f), f in revolutions
__device__ __forceinline__ v2f twid(float f) {
    float s, c;
#if __has_builtin(__builtin_amdgcn_sinf) && __has_builtin(__builtin_amdgcn_cosf)
    s = __builtin_amdgcn_sinf(f);
    c = __builtin_amdgcn_cosf(f);
#else
    __sincosf(6.28318530717958647693f * f, &s, &c);
#endif
    return mk(c, -s);
}

// radix-4 DIF butterfly
__device__ __forceinline__ void bfly4(v2f c0, v2f c1, v2f c2, v2f c3,
                                      v2f& e0, v2f& e1, v2f& e2, v2f& e3) {
    v2f d0 = c0 + c2, d1 = c0 - c2;
    v2f d2 = c1 + c3, d3 = mulnegi(c1 - c3);
    e0 = d0 + d2; e1 = d1 + d3; e2 = d0 - d2; e3 = d1 - d3;
}

// 16-point DFT, natural order in/out
__device__ __forceinline__ void fft16(v2f v[16]) {
    const float C1 = 0.92387953251128675613f;
    const float S1 = 0.38268343236508977173f;
    const float RH = 0.70710678118654752440f;
    const v2f W1 = mk( C1, -S1);
    const v2f W2 = mk( RH, -RH);
    const v2f W3 = mk( S1, -C1);
    const v2f W6 = mk(-RH, -RH);
    const v2f W9 = mk(-C1,  S1);
    v2f t[16];
    { v2f e0,e1,e2,e3; bfly4(v[0],v[4],v[8],v[12], e0,e1,e2,e3);
      t[0]=e0; t[1]=e1; t[2]=e2; t[3]=e3; }
    { v2f e0,e1,e2,e3; bfly4(v[1],v[5],v[9],v[13], e0,e1,e2,e3);
      t[4]=e0; t[5]=cmul(e1,W1); t[6]=cmul(e2,W2); t[7]=cmul(e3,W3); }
    { v2f e0,e1,e2,e3; bfly4(v[2],v[6],v[10],v[14], e0,e1,e2,e3);
      t[8]=e0; t[9]=cmul(e1,W2); t[10]=mulnegi(e2); t[11]=cmul(e3,W6); }
    { v2f e0,e1,e2,e3; bfly4(v[3],v[7],v[11],v[15], e0,e1,e2,e3);
      t[12]=e0; t[13]=cmul(e1,W3); t[14]=cmul(e2,W6); t[15]=cmul(e3,W9); }
    { v2f e0,e1,e2,e3; bfly4(t[0],t[4],t[8],t[12], e0,e1,e2,e3);
      v[0]=e0; v[4]=e1; v[8]=e2; v[12]=e3; }
    { v2f e0,e1,e2,e3; bfly4(t[1],t[5],t[9],t[13], e0,e1,e2,e3);
      v[1]=e0; v[5]=e1; v[9]=e2; v[13]=e3; }
    { v2f e0,e1,e2,e3; bfly4(t[2],t[6],t[10],t[14], e0,e1,e2,e3);
      v[2]=e0; v[6]=e1; v[10]=e2; v[14]=e3; }
    { v2f e0,e1,e2,e3; bfly4(t[3],t[7],t[11],t[15], e0,e1,e2,e3);
      v[3]=e0; v[7]=e1; v[11]=e2; v[15]=e3; }
}

// 8-point DFT, natural order in/out
__device__ __forceinline__ void fft8(v2f v[8]) {
    const float RH = 0.70710678118654752440f;
    v2f e0,e1,e2,e3, o0,o1,o2,o3;
    bfly4(v[0],v[2],v[4],v[6], e0,e1,e2,e3);
    bfly4(v[1],v[3],v[5],v[7], o0,o1,o2,o3);
    o1 = cmul(o1, mk( RH,-RH));
    o2 = mulnegi(o2);
    o3 = cmul(o3, mk(-RH,-RH));
    v[0]=e0+o0; v[4]=e0-o0;
    v[1]=e1+o1; v[5]=e1-o1;
    v[2]=e2+o2; v[6]=e2-o2;
    v[3]=e3+o3; v[7]=e3-o3;
}

// Scaled W for stored Z_s = Z * 2^-2: returns W * 2^-14
__device__ __forceinline__ v2f Wfun_s(v2f sk, v2f sr) {
    v2f a2 = cmul(sk, sk);
    v2f cs = conjv(sr);
    v2f b2 = cmul(cs, cs);
    v2f d  = a2 - b2;
    return mulnegi(d) * (1.0f / 4096.0f);
}

// ---------------------------------------------------------------------------
// 1024-thread geometry: tile = 64 cols x 256 q (radix-256) / 128 x 128 (r-128).
// thread = (col = t&63, sl = t>>6); a WAVE's 64 lanes span 64 consecutive cols
// -> every global load/store instruction covers a 256B contiguous segment.
// LDS: 64 KB exact, XOR swizzle p ^ (col&31).
// launch_bounds(1024, 4): VGPR cap 128 -> NO SPILL (round 16's (1024,8)
// forced VGPR=32 and spilled ~63MB/pass; this is the only change).
// MODE 0: fwd A (N2, l=65536), pack fused, staged j-major out
// MODE 1: fwd B (N2, l=256),   direct k-major store
// MODE 2: fwd C (N2, l=1),     direct store, Z_s = Z*2^-2
// MODE 3: inv A (M, l=32768),  pw fused + mirror-pair XCD swizzle (512 blocks)
// MODE 4: inv B (M, l=128),    direct store, amp 2^-4
// MODE 5: inv C (M, radix-128),fp32 interleaved-real out, *0.5
// Arithmetic identical to rounds 13/15/16 -> absmax must stay 64.
// ---------------------------------------------------------------------------
template<int MODE>
__global__ __launch_bounds__(1024, 4)
void fft_pass(const float* __restrict__ ga, const float* __restrict__ gx,
              const __half2* __restrict__ gin, __half2* __restrict__ gout,
              float2* __restrict__ goutF) {
    __shared__ __half2 tile[16384];   // exactly 64 KB
    const int t = threadIdx.x;
    int blk = blockIdx.x;
    if constexpr (MODE == 3) {
        // mirror-pair XCD swizzle over 512 blocks: regions p and 511-p placed
        // 8 apart in blockIdx -> same XCD under round-robin assignment
        int g = blk >> 4, i = blk & 15;
        blk = (i < 8) ? (8 * g + i) : (511 - (8 * g + (i - 8)));
    }

    if constexpr (MODE == 5) {
        // ---- radix-128 final pass: 128 cols x 128 q ----
        const int col = t & 127;
        const int sl  = t >> 7;           // [0,8)
        const int mk_ = col & 31;
        const int cb  = col << 7;         // col * 128
        const int bi  = blk * 128 + col;

        v2f va[8], vb[8];
        #pragma unroll
        for (int u2 = 0; u2 < 8; ++u2)
            va[u2] = h2f(gin[bi + ((sl + 16 * u2) << 16)]);
        #pragma unroll
        for (int u2 = 0; u2 < 8; ++u2)
            vb[u2] = h2f(gin[bi + ((sl + 8 + 16 * u2) << 16)]);
        fft8(va); fft8(vb);
        {   // layer-1 twiddles via recurrence (chain <= 7)
            v2f w1a = twid((float)sl * (1.0f / 128.0f));
            v2f w1b = twid((float)(sl + 8) * (1.0f / 128.0f));
            v2f ca = w1a, cb2 = w1b;
            va[1] = cmul(va[1], ca); vb[1] = cmul(vb[1], cb2);
            #pragma unroll
            for (int r2 = 2; r2 < 8; ++r2) {
                ca = cmul(ca, w1a);  va[r2] = cmul(va[r2], ca);
                cb2 = cmul(cb2, w1b); vb[r2] = cmul(vb[r2], cb2);
            }
        }
        #pragma unroll
        for (int r2 = 0; r2 < 8; ++r2) {
            tile[cb + ((sl + 16 * r2) ^ mk_)]     = f2h(va[r2]);
            tile[cb + ((sl + 8 + 16 * r2) ^ mk_)] = f2h(vb[r2]);
        }
        __syncthreads();
        v2f w[16];
        #pragma unroll
        for (int q1 = 0; q1 < 16; ++q1)
            w[q1] = h2f(tile[cb + ((q1 + 16 * sl) ^ mk_)]);
        fft16(w);   // w[r1] -> output r = sl + 8*r1, keep r < 64

        const float sc = 0.5f;            // accumulated scale; y = G/2^23
        #pragma unroll
        for (int r1 = 0; r1 < 8; ++r1) {
            int r = sl + 8 * r1;
            goutF[bi + (r << 16)] = make_float2(w[r1].x * sc, -w[r1].y * sc);
        }
        return;
    } else {
        // ---- radix-256 pass: 64 cols x 256 q ----
        const int col = t & 63;
        const int sl  = t >> 6;           // [0,16)
        const int mk_ = col & 31;
        const int cb  = col << 8;         // col * 256
        v2f v[16];
        int jt = 0;

        if constexpr (MODE == 0) {        // fwd A, pack fused (q>=128 zero)
            int j = blk * 64 + col;
            jt = j;
            #pragma unroll
            for (int u2 = 0; u2 < 16; ++u2) {
                if (u2 < 8) {
                    int g = j + ((sl + 16 * u2) << 16);   // < N_SIG
                    v[u2] = mk(ga[g], gx[g]);
                } else {
                    v[u2] = mk(0.f, 0.f);
                }
            }
        } else if constexpr (MODE == 3) { // inv A: pw fused, contiguous-j gather
            int j = blk * 64 + col;       // j in [0, 2^15)
            jt = j;
            const float RH = 0.70710678118654752440f;
            v2f eb = twid((float)(j + (sl << 15)) * (1.0f / 16777216.0f));
            const v2f estep = mk(0.98078528040323044913f, -0.19509032201612826785f);
            v2f ec = eb;
            #pragma unroll
            for (int u2 = 0; u2 < 16; ++u2) {
                int tp = j + ((sl + 16 * u2) << 15);        // [0, M)
                v2f z1 = h2f(gin[tp]);                      // Z[t]
                v2f z2 = h2f(gin[tp + MH]);                 // Z[t+M]
                v2f z3 = h2f(gin[(N2 - tp) & (N2 - 1)]);    // Z[N2-t]
                v2f z4 = h2f(gin[MH - tp]);                 // Z[M-t]
                v2f Wt  = Wfun_s(z1, z3);
                v2f WtM = Wfun_s(z2, z4);
                v2f S = (Wt + WtM) * 0.5f;
                v2f D = (Wt - WtM) * 0.5f;
                v2f T = cmul(conjv(ec), D);                 // e^{+i th} * D
                v2f U = S + mk(-T.y, T.x);                  // S + i*T
                v[u2] = conjv(U);                           // P_s[t]
                if (u2 == 3)       ec = cmul(eb, mk(RH, -RH));   // *twid(1/8)
                else if (u2 == 7)  ec = mulnegi(eb);             // *twid(1/4)
                else if (u2 == 11) ec = cmul(eb, mk(-RH, -RH));  // *twid(3/8)
                else               ec = cmul(ec, estep);
            }
        } else if constexpr (MODE == 1) { // fwd B
            int jB = blk >> 2, k0 = (blk & 3) * 64;
            int bi = k0 + col + (jB << 8);
            jt = jB;
            #pragma unroll
            for (int u2 = 0; u2 < 16; ++u2)
                v[u2] = h2f(gin[bi + ((sl + 16 * u2) << 16)]);
        } else if constexpr (MODE == 4) { // inv B (half length, stride 2^15)
            int jB = blk >> 2, k0 = (blk & 3) * 64;
            int bi = k0 + col + (jB << 8);
            jt = jB;
            #pragma unroll
            for (int u2 = 0; u2 < 16; ++u2)
                v[u2] = h2f(gin[bi + ((sl + 16 * u2) << 15)]);
        } else {                          // MODE 2: fwd C
            int bi = blk * 64 + col;
            #pragma unroll
            for (int u2 = 0; u2 < 16; ++u2)
                v[u2] = h2f(gin[bi + ((sl + 16 * u2) << 16)]);
        }

        // layer 1: FFT16 over u2, twiddle W256^{sl*r2}, reseed at r=8
        fft16(v);
        {
            v2f w1 = twid((float)sl * (1.0f / 256.0f));
            v2f w8 = twid((float)sl * (1.0f / 32.0f));
            v2f cw = w1;
            v[1] = cmul(v[1], cw);
            #pragma unroll
            for (int r = 2; r < 16; ++r) {
                cw = (r == 8) ? w8 : cmul(cw, w1);
                v[r] = cmul(v[r], cw);
            }
        }

        // transpose: write p = sl + 16*r2, XOR swizzle
        #pragma unroll
        for (int r = 0; r < 16; ++r)
            tile[cb + ((sl + 16 * r) ^ mk_)] = f2h(v[r]);
        __syncthreads();
        v2f w[16];
        #pragma unroll
        for (int u1 = 0; u1 < 16; ++u1)
            w[u1] = h2f(tile[cb + ((u1 + 16 * sl) ^ mk_)]);
        if constexpr (MODE == 0 || MODE == 3)
            __syncthreads();               // readers done before staging overwrite

        fft16(w);

        // outer twiddle base*step^r1 (reseed at r1=8); MODE3/4 fold 2^-4
        if constexpr (MODE != 2) {
            float base_rev, step_rev, amp;
            if constexpr (MODE == 0) {        // D = 2^24
                base_rev = (float)(jt * sl) * (1.0f / 16777216.0f);
                step_rev = (float)jt * (1.0f / 1048576.0f);
                amp = 1.0f;
            } else if constexpr (MODE == 3) { // D = 2^23
                base_rev = (float)(jt * sl) * (1.0f / 8388608.0f);
                step_rev = (float)jt * (1.0f / 524288.0f);
                amp = 0.0625f;
            } else if constexpr (MODE == 1) { // D = 65536
                base_rev = (float)(jt * sl) * (1.0f / 65536.0f);
                step_rev = (float)jt * (1.0f / 4096.0f);
                amp = 1.0f;
            } else {                          // MODE 4: D = 32768
                base_rev = (float)(jt * sl) * (1.0f / 32768.0f);
                step_rev = (float)jt * (1.0f / 2048.0f);
                amp = 0.0625f;
            }
            v2f b0 = twid(base_rev) * amp;
            v2f os = twid(step_rev);
            v2f b8 = twid(base_rev + 8.0f * step_rev) * amp;
            v2f ob = b0;
            w[0] = cmul(w[0], ob);
            #pragma unroll
            for (int r1 = 1; r1 < 16; ++r1) {
                ob = (r1 == 8) ? b8 : cmul(ob, os);
                w[r1] = cmul(w[r1], ob);
            }
        }

        if constexpr (MODE == 0 || MODE == 3) {
            // j-major out[256 j + r], j = blk*64 + col: stage at p = sl+16*r1,
            // then one 16384-element linear sweep (16/thread, 64B contiguous)
            #pragma unroll
            for (int r1 = 0; r1 < 16; ++r1)
                tile[cb + ((sl + 16 * r1) ^ mk_)] = f2h(w[r1]);
            __syncthreads();
            int base = blk << 14;
            int rr = t >> 4;                 // output col [0,64)
            int c0 = (t & 15) << 4;          // r base
            int rbq = rr << 8;
            int rm = rr & 31;
            __half2* gp = &gout[base + (t << 4)];
            #pragma unroll
            for (int i = 0; i < 16; ++i)
                gp[i] = tile[rbq + ((c0 + i) ^ rm)];
        } else if constexpr (MODE == 1 || MODE == 4) {
            // k-major out[k + 65536 j + 256 r]: direct, 64-lane 256B runs
            int jB = blk >> 2, k0 = (blk & 3) * 64;
            int base = k0 + (jB << 16) + col;
            #pragma unroll
            for (int r1 = 0; r1 < 16; ++r1)
                gout[base + ((sl + 16 * r1) << 8)] = f2h(w[r1]);
        } else {
            // MODE 2: out[k + 65536 r]: direct, Z_s = Z * 2^-2
            int base = blk * 64 + col;
            #pragma unroll
            for (int r1 = 0; r1 < 16; ++r1)
                gout[base + ((sl + 16 * r1) << 16)] = f2h(w[r1] * 0.25f);
        }
    }
}

extern "C" void kernel_launch(void* const* d_in, const int* in_sizes, int n_in,
                              void* d_out, int out_size, void* d_ws, size_t ws_size,
                              hipStream_t stream) {
    const float* a = (const float*)d_in[0];
    const float* x = (const float*)d_in[1];
    float2* out2 = (float2*)d_out;

    __half2* buf0 = (__half2*)d_ws;     // 64 MB
    __half2* buf1 = buf0 + N2;          // 64 MB

    dim3 b(1024);
    // forward FFT of z = a + i*x, length 2^24
    fft_pass<0><<<1024, b, 0, stream>>>(a, x, nullptr, buf0, nullptr);
    fft_pass<1><<<1024, b, 0, stream>>>(nullptr, nullptr, buf0, buf1, nullptr);
    fft_pass<2><<<1024, b, 0, stream>>>(nullptr, nullptr, buf1, buf0, nullptr);
    // inverse via half-length forward FFT; Hermitian pointwise fused into the
    // stage-A load; mirror-pair XCD swizzle makes mirror gathers L2-local
    fft_pass<3><<<512, b, 0, stream>>>(nullptr, nullptr, buf0, buf1, nullptr);
    fft_pass<4><<<512, b, 0, stream>>>(nullptr, nullptr, buf1, buf0, nullptr);
    fft_pass<5><<<512, b, 0, stream>>>(nullptr, nullptr, buf0, nullptr, out2);
}

// Round 18
// 135.666 us; speedup vs baseline: 1.5483x; 1.2697x over previous
//
#include <hip/hip_runtime.h>
#include <hip/hip_fp16.h>

#define N_SIG (1 << 23)   // 8388608
#define N2    (1 << 24)   // padded FFT length = 256^3
#define MH    (1 << 23)   // half length M = 2^23 = 256*256*128
#define LP    258         // padded LDS row stride (radix-256 tiles): 2-way banks, imm offsets
#define LP5   130         // padded LDS row stride (radix-128 tile)

// ---------------------------------------------------------------------------
// packed-f32 complex type
// ---------------------------------------------------------------------------
typedef float v2f __attribute__((ext_vector_type(2)));

__device__ __forceinline__ v2f mk(float x, float y) { v2f r; r.x = x; r.y = y; return r; }
__device__ __forceinline__ v2f cmul(v2f a, v2f b) {
    return mk(a.x, a.x) * b + mk(-a.y, a.y) * __builtin_shufflevector(b, b, 1, 0);
}
__device__ __forceinline__ v2f mulnegi(v2f a) { return mk(a.y, -a.x); }   // -i*a
__device__ __forceinline__ v2f conjv(v2f a)  { return mk(a.x, -a.y); }

__device__ __forceinline__ v2f h2f(__half2 h) {
    return mk(__low2float(h), __high2float(h));
}
__device__ __forceinline__ __half2 f2h(v2f f) {
    return __float22half2_rn(make_float2(f.x, f.y));
}

// exp(-2*pi*i*f), f in revolutions
__device__ __forceinline__ v2f twid(float f) {
    float s, c;
#if __has_builtin(__builtin_amdgcn_sinf) && __has_builtin(__builtin_amdgcn_cosf)
    s = __builtin_amdgcn_sinf(f);
    c = __builtin_amdgcn_cosf(f);
#else
    __sincosf(6.28318530717958647693f * f, &s, &c);
#endif
    return mk(c, -s);
}

// radix-4 DIF butterfly = natural-order 4-point DFT (negative exponent)
__device__ __forceinline__ void bfly4(v2f c0, v2f c1, v2f c2, v2f c3,
                                      v2f& e0, v2f& e1, v2f& e2, v2f& e3) {
    v2f d0 = c0 + c2, d1 = c0 - c2;
    v2f d2 = c1 + c3, d3 = mulnegi(c1 - c3);
    e0 = d0 + d2; e1 = d1 + d3; e2 = d0 - d2; e3 = d1 - d3;
}

// 16-point DFT, natural order in/out
__device__ __forceinline__ void fft16(v2f v[16]) {
    const float C1 = 0.92387953251128675613f;
    const float S1 = 0.38268343236508977173f;
    const float RH = 0.70710678118654752440f;
    const v2f W1 = mk( C1, -S1);
    const v2f W2 = mk( RH, -RH);
    const v2f W3 = mk( S1, -C1);
    const v2f W6 = mk(-RH, -RH);
    const v2f W9 = mk(-C1,  S1);
    v2f t[16];
    { v2f e0,e1,e2,e3; bfly4(v[0],v[4],v[8],v[12], e0,e1,e2,e3);
      t[0]=e0; t[1]=e1; t[2]=e2; t[3]=e3; }
    { v2f e0,e1,e2,e3; bfly4(v[1],v[5],v[9],v[13], e0,e1,e2,e3);
      t[4]=e0; t[5]=cmul(e1,W1); t[6]=cmul(e2,W2); t[7]=cmul(e3,W3); }
    { v2f e0,e1,e2,e3; bfly4(v[2],v[6],v[10],v[14], e0,e1,e2,e3);
      t[8]=e0; t[9]=cmul(e1,W2); t[10]=mulnegi(e2); t[11]=cmul(e3,W6); }
    { v2f e0,e1,e2,e3; bfly4(v[3],v[7],v[11],v[15], e0,e1,e2,e3);
      t[12]=e0; t[13]=cmul(e1,W3); t[14]=cmul(e2,W6); t[15]=cmul(e3,W9); }
    { v2f e0,e1,e2,e3; bfly4(t[0],t[4],t[8],t[12], e0,e1,e2,e3);
      v[0]=e0; v[4]=e1; v[8]=e2; v[12]=e3; }
    { v2f e0,e1,e2,e3; bfly4(t[1],t[5],t[9],t[13], e0,e1,e2,e3);
      v[1]=e0; v[5]=e1; v[9]=e2; v[13]=e3; }
    { v2f e0,e1,e2,e3; bfly4(t[2],t[6],t[10],t[14], e0,e1,e2,e3);
      v[2]=e0; v[6]=e1; v[10]=e2; v[14]=e3; }
    { v2f e0,e1,e2,e3; bfly4(t[3],t[7],t[11],t[15], e0,e1,e2,e3);
      v[3]=e0; v[7]=e1; v[11]=e2; v[15]=e3; }
}

// 8-point DFT, natural order in/out
__device__ __forceinline__ void fft8(v2f v[8]) {
    const float RH = 0.70710678118654752440f;
    v2f e0,e1,e2,e3, o0,o1,o2,o3;
    bfly4(v[0],v[2],v[4],v[6], e0,e1,e2,e3);
    bfly4(v[1],v[3],v[5],v[7], o0,o1,o2,o3);
    o1 = cmul(o1, mk( RH,-RH));
    o2 = mulnegi(o2);
    o3 = cmul(o3, mk(-RH,-RH));
    v[0]=e0+o0; v[4]=e0-o0;
    v[1]=e1+o1; v[5]=e1-o1;
    v[2]=e2+o2; v[6]=e2-o2;
    v[3]=e3+o3; v[7]=e3-o3;
}

// Scaled W for stored Z_s = Z * 2^-2: returns W * 2^-14 = -i*2^-12*(sk^2 - conj(sr)^2)
__device__ __forceinline__ v2f Wfun_s(v2f sk, v2f sr) {
    v2f a2 = cmul(sk, sk);
    v2f cs = conjv(sr);
    v2f b2 = cmul(cs, cs);
    v2f d  = a2 - b2;
    return mulnegi(d) * (1.0f / 4096.0f);
}

// ---------------------------------------------------------------------------
// MODE 0: fwd stage A  (N2, radix-256, l=65536), pack fused, staged j-major out
// MODE 1: fwd stage B  (N2, radix-256, l=256),  direct k-major store
// MODE 2: fwd stage C  (N2, radix-256, l=1),    direct store, Z_s = Z*2^-2
// MODE 3: inv stage A  (M,  radix-256, l=32768), pw fused (contiguous-j gather,
//         j = blk*32+row) + mirror-pair XCD swizzle; staged j-major out with
//         the same single blk<<13 sweep as MODE 0.
// MODE 4: inv stage B  (M,  radix-256, l=128),  direct store, amp 2^-4
// MODE 5: inv stage C  (M,  radix-128, l=1),    fp32 interleaved-real out, *0.5
// LDS: padded-stride layout (LP=258 / LP5=130):
//  - banks: stride%32==2 -> 2-way aliasing (free, m136)
//  - every DS access is base_reg + compile-time imm offset
//  - layer-2 reads are consecutive -> ds_read_b64 merges
// ---------------------------------------------------------------------------
template<int MODE>
__global__ __launch_bounds__(512, 4)
void fft_pass(const float* __restrict__ ga, const float* __restrict__ gx,
              const __half2* __restrict__ gin, __half2* __restrict__ gout,
              float2* __restrict__ goutF) {
    __shared__ __half2 tile[8320];   // 33.3 KB (covers 32*258=8256 and 64*130=8320)
    const int t   = threadIdx.x;
    int blk = blockIdx.x;
    if constexpr (MODE == 3) {
        // mirror-pair XCD swizzle: bb=16g+i -> pb = 8g+i (i<8) | 1023-(8g+i-8)
        int g = blk >> 4, i = blk & 15;
        blk = (i < 8) ? (8 * g + i) : (1023 - (8 * g + (i - 8)));
    }

    if constexpr (MODE == 5) {
        // ---- radix-128 final pass: 64 rows x 128 pts, slot in [0,8) ----
        const int row  = t & 63;
        const int slot = t >> 6;
        const int bi   = blk * 64 + row;

        v2f va[8], vb[8];
        #pragma unroll
        for (int u2 = 0; u2 < 8; ++u2)
            va[u2] = h2f(gin[bi + ((slot + 16 * u2) << 16)]);
        #pragma unroll
        for (int u2 = 0; u2 < 8; ++u2)
            vb[u2] = h2f(gin[bi + ((slot + 8 + 16 * u2) << 16)]);
        fft8(va); fft8(vb);
        {   // layer-1 twiddles via recurrence (chain <= 7)
            v2f w1a = twid((float)slot * (1.0f / 128.0f));
            v2f w1b = twid((float)(slot + 8) * (1.0f / 128.0f));
            v2f ca = w1a, cb = w1b;
            va[1] = cmul(va[1], ca); vb[1] = cmul(vb[1], cb);
            #pragma unroll
            for (int r2 = 2; r2 < 8; ++r2) {
                ca = cmul(ca, w1a); va[r2] = cmul(va[r2], ca);
                cb = cmul(cb, w1b); vb[r2] = cmul(vb[r2], cb);
            }
        }
        {   // padded layout: base + imm offsets
            __half2* wp = &tile[row * LP5 + slot];
            #pragma unroll
            for (int r2 = 0; r2 < 8; ++r2) {
                wp[16 * r2]     = f2h(va[r2]);
                wp[8 + 16 * r2] = f2h(vb[r2]);
            }
        }
        __syncthreads();
        v2f w[16];
        {
            const __half2* rp = &tile[row * LP5 + 16 * slot];
            #pragma unroll
            for (int q1 = 0; q1 < 16; ++q1)
                w[q1] = h2f(rp[q1]);
        }
        fft16(w);   // w[r1] -> output r = slot + 8*r1

        const float sc = 0.5f;          // accumulated scale 2^-22; y = G/2^23
        const int k0 = blk * 64;
        #pragma unroll
        for (int r1 = 0; r1 < 8; ++r1) {
            int r = slot + 8 * r1;      // < 64
            goutF[k0 + row + (r << 16)] = make_float2(w[r1].x * sc, -w[r1].y * sc);
        }
        return;
    } else {
        // ---- radix-256 pass: 32 rows x 256 pts, slot in [0,16) ----
        const int row  = t & 31;
        const int slot = t >> 5;
        v2f v[16];
        int jt = 0;

        if constexpr (MODE == 0) {          // fwd A, pack fused (q>=128 zero)
            int j = blk * 32 + row;
            jt = j;
            #pragma unroll
            for (int u2 = 0; u2 < 16; ++u2) {
                if (u2 < 8) {
                    int g = j + ((slot + 16 * u2) << 16);   // < N_SIG
                    v[u2] = mk(ga[g], gx[g]);
                } else {
                    v[u2] = mk(0.f, 0.f);
                }
            }
        } else if constexpr (MODE == 3) {   // inv A: pw fused (contiguous-j gather)
            int j = blk * 32 + row;          // j in [0, 2^15)
            jt = j;
            // pw twiddle recurrence: f(t) = (j + slot*2^15)/2^24 + u2/32
            const float RH = 0.70710678118654752440f;
            v2f eb = twid((float)(j + (slot << 15)) * (1.0f / 16777216.0f));
            const v2f estep = mk(0.98078528040323044913f, -0.19509032201612826785f);
            v2f ec = eb;
            #pragma unroll
            for (int u2 = 0; u2 < 16; ++u2) {
                int tp = j + ((slot + 16 * u2) << 15);       // [0, M)
                v2f z1 = h2f(gin[tp]);                       // Z[t]
                v2f z2 = h2f(gin[tp + MH]);                  // Z[t+M]
                v2f z3 = h2f(gin[(N2 - tp) & (N2 - 1)]);     // Z[N2-t]
                v2f z4 = h2f(gin[MH - tp]);                  // Z[M-t]
                v2f Wt  = Wfun_s(z1, z3);                    // W[t]   * 2^-14
                v2f WtM = Wfun_s(z2, z4);                    // W[t+M] * 2^-14
                v2f S = (Wt + WtM) * 0.5f;
                v2f D = (Wt - WtM) * 0.5f;
                v2f T = cmul(conjv(ec), D);                  // e^{+i th} * D
                v2f U = S + mk(-T.y, T.x);                   // S + i*T
                v[u2] = conjv(U);                            // P_s[t]
                // advance ec; exact reseeds at u2 = 4, 8, 12
                if (u2 == 3)       ec = cmul(eb, mk(RH, -RH));   // *twid(1/8)
                else if (u2 == 7)  ec = mulnegi(eb);             // *twid(1/4) = -i
                else if (u2 == 11) ec = cmul(eb, mk(-RH, -RH));  // *twid(3/8)
                else               ec = cmul(ec, estep);
            }
        } else if constexpr (MODE == 1) {   // fwd B
            int jB = blk >> 3, k0 = (blk & 7) * 32;
            int bi = k0 + row + (jB << 8);
            jt = jB;
            #pragma unroll
            for (int u2 = 0; u2 < 16; ++u2)
                v[u2] = h2f(gin[bi + ((slot + 16 * u2) << 16)]);
        } else if constexpr (MODE == 4) {   // inv B (half length, stride 2^15)
            int jB = blk >> 3, k0 = (blk & 7) * 32;
            int bi = k0 + row + (jB << 8);
            jt = jB;
            #pragma unroll
            for (int u2 = 0; u2 < 16; ++u2)
                v[u2] = h2f(gin[bi + ((slot + 16 * u2) << 15)]);
        } else {                            // MODE 2: fwd C
            int bi = blk * 32 + row;
            #pragma unroll
            for (int u2 = 0; u2 < 16; ++u2)
                v[u2] = h2f(gin[bi + ((slot + 16 * u2) << 16)]);
        }

        // layer 1: FFT16 over u2, twiddle W256^{slot*r}, reseed at r=8
        fft16(v);
        {
            v2f w1 = twid((float)slot * (1.0f / 256.0f));
            v2f w8 = twid((float)slot * (1.0f / 32.0f));
            v2f cw = w1;
            v[1] = cmul(v[1], cw);
            #pragma unroll
            for (int r = 2; r < 16; ++r) {
                cw = (r == 8) ? w8 : cmul(cw, w1);
                v[r] = cmul(v[r], cw);
            }
        }

        // transpose via padded LDS: write q = slot + 16r (imm offsets)
        {
            __half2* wp = &tile[row * LP + slot];
            #pragma unroll
            for (int r = 0; r < 16; ++r)
                wp[16 * r] = f2h(v[r]);
        }
        __syncthreads();
        v2f w[16];
        {   // read q = u1 + 16*slot: consecutive -> ds_read_b64 merges
            const __half2* rp = &tile[row * LP + 16 * slot];
            #pragma unroll
            for (int u1 = 0; u1 < 16; ++u1)
                w[u1] = h2f(rp[u1]);
        }
        if constexpr (MODE == 0 || MODE == 3)
            __syncthreads();                 // readers done before staging overwrite

        fft16(w);

        // outer twiddle base*step^v2 (reseed at v2=8); MODE3/4 fold 2^-4 scale
        {
            float base_rev, step_rev, amp;
            if constexpr (MODE == 0) {       // D = 2^24
                base_rev = (float)(jt * slot) * (1.0f / 16777216.0f);
                step_rev = (float)jt * (1.0f / 1048576.0f);
                amp = 1.0f;
            } else if constexpr (MODE == 3) {// D = 2^23
                base_rev = (float)(jt * slot) * (1.0f / 8388608.0f);
                step_rev = (float)jt * (1.0f / 524288.0f);
                amp = 0.0625f;
            } else if constexpr (MODE == 1) {// D = 65536
                base_rev = (float)(jt * slot) * (1.0f / 65536.0f);
                step_rev = (float)jt * (1.0f / 4096.0f);
                amp = 1.0f;
            } else {                         // MODE 2 unused / MODE 4: D = 32768
                base_rev = (float)(jt * slot) * (1.0f / 32768.0f);
                step_rev = (float)jt * (1.0f / 2048.0f);
                amp = 0.0625f;
            }
            if constexpr (MODE != 2) {
                v2f b0 = twid(base_rev) * amp;
                v2f os = twid(step_rev);
                v2f b8 = twid(base_rev + 8.0f * step_rev) * amp;
                v2f ob = b0;
                w[0] = cmul(w[0], ob);
                #pragma unroll
                for (int v2 = 1; v2 < 16; ++v2) {
                    ob = (v2 == 8) ? b8 : cmul(ob, os);
                    w[v2] = cmul(w[v2], ob);
                }
            }
        }

        if constexpr (MODE == 0 || MODE == 3) {
            // j-major out[256 j + r], j = blk*32 + row: stage (imm offsets),
            // single blk<<13 sweep, 4-wide (merges to dwordx4)
            {
                __half2* wp = &tile[row * LP + slot];
                #pragma unroll
                for (int v2 = 0; v2 < 16; ++v2)
                    wp[16 * v2] = f2h(w[v2]);
            }
            __syncthreads();
            int base = blk << 13;
            #pragma unroll
            for (int i = 0; i < 4; ++i) {
                int s0 = (t + 512 * i) * 4;
                int rr = s0 >> 8, c = s0 & 255;
                const __half2* lp = &tile[rr * LP + c];
                __half2* gp = &gout[base + s0];
                gp[0] = lp[0]; gp[1] = lp[1]; gp[2] = lp[2]; gp[3] = lp[3];
            }
        } else if constexpr (MODE == 1 || MODE == 4) {
            // k-major out[k + 65536 j + 256 r]: direct store (32-wide runs)
            int jB = blk >> 3, k0 = (blk & 7) * 32;
            int base = k0 + (jB << 16) + row;
            #pragma unroll
            for (int v2 = 0; v2 < 16; ++v2)
                gout[base + ((slot + 16 * v2) << 8)] = f2h(w[v2]);
        } else {
            // MODE 2: out[k + 65536 r]: direct store, Z_s = Z * 2^-2
            int base = blk * 32 + row;
            #pragma unroll
            for (int v2 = 0; v2 < 16; ++v2)
                gout[base + ((slot + 16 * v2) << 16)] = f2h(w[v2] * 0.25f);
        }
    }
}

extern "C" void kernel_launch(void* const* d_in, const int* in_sizes, int n_in,
                              void* d_out, int out_size, void* d_ws, size_t ws_size,
                              hipStream_t stream) {
    const float* a = (const float*)d_in[0];
    const float* x = (const float*)d_in[1];
    float2* out2 = (float2*)d_out;

    __half2* buf0 = (__half2*)d_ws;     // 64 MB
    __half2* buf1 = buf0 + N2;          // 64 MB

    dim3 b(512);
    // forward FFT of z = a + i*x, length 2^24
    fft_pass<0><<<2048, b, 0, stream>>>(a, x, nullptr, buf0, nullptr);
    fft_pass<1><<<2048, b, 0, stream>>>(nullptr, nullptr, buf0, buf1, nullptr);
    fft_pass<2><<<2048, b, 0, stream>>>(nullptr, nullptr, buf1, buf0, nullptr);
    // inverse via half-length forward FFT; Hermitian pointwise fused into the
    // stage-A load; mirror-pair XCD swizzle makes mirror gathers L2-local
    fft_pass<3><<<1024, b, 0, stream>>>(nullptr, nullptr, buf0, buf1, nullptr);
    fft_pass<4><<<1024, b, 0, stream>>>(nullptr, nullptr, buf1, buf0, nullptr);
    fft_pass<5><<<1024, b, 0, stream>>>(nullptr, nullptr, buf0, nullptr, out2);
}